// Round 1
// baseline (133.175 us; speedup 1.0000x reference)
//
#include <hip/hip_runtime.h>
#include <hip/hip_bf16.h>
#include <stdint.h>

#define GAT_ALPHA 0.2f
#define LOG2E 1.4426950408889634f

typedef __attribute__((ext_vector_type(8))) short bf16x8;
typedef __attribute__((ext_vector_type(8))) unsigned short ushort8;
typedef __attribute__((ext_vector_type(4))) float f32x4;

// ---------------- K0: pack adjacency int32 -> bitmask (64MB -> 2MB) --------
__global__ __launch_bounds__(256) void k_pack_adj(const int* __restrict__ adj,
                                                  unsigned long long* __restrict__ packed,
                                                  int nwords) {
    int gid = blockIdx.x * 256 + threadIdx.x;
    int wid = gid >> 6;               // one 64-bit word per wave
    int lane = threadIdx.x & 63;
    if (wid >= nwords) return;
    int v = adj[(size_t)wid * 64 + lane];
    unsigned long long m = __ballot(v > 0);
    if (lane == 0) packed[wid] = m;
}

// ---------------- K1: Wh = h@W[h]; Wh1/Wh2 (pre-scaled by log2e); WhT bf16 -
__global__ __launch_bounds__(256) void k_wh(const float* __restrict__ hmat,   // [4096][256]
                                            const float* __restrict__ Wmat,   // [8][256][32]
                                            const float* __restrict__ avec,   // [8][64]
                                            float* __restrict__ wh1s,         // [8][4096]  *log2e
                                            float* __restrict__ wh2s,         // [8][4096]  *log2e
                                            unsigned short* __restrict__ whT) // [8][32][4096] bf16
{
    const int head = blockIdx.y;
    const int nbase = blockIdx.x * 64;
    const int t = threadIdx.x;
    const int d = t & 31, nl = t >> 5;

    __shared__ float WT[32][260];   // W transposed [d][i], pad -> 4-way max conflict
    __shared__ float hl[8][256];    // staged h rows
    __shared__ float tr[64][33];    // transpose buffer for WhT write, pad 33

    #pragma unroll
    for (int k = 0; k < 32; ++k) {
        int idx = t + k * 256;
        int ii = idx >> 5, dd = idx & 31;
        WT[dd][ii] = Wmat[(head * 256 + ii) * 32 + dd];
    }
    float a1 = avec[head * 64 + d];
    float a2 = avec[head * 64 + 32 + d];

    for (int c = 0; c < 8; ++c) {
        __syncthreads();
        {   // stage 8 rows of h (each thread: 8 floats = 2x float4)
            const float4* src = (const float4*)&hmat[(size_t)(nbase + c * 8 + nl) * 256 + d * 8];
            float4* dst = (float4*)&hl[nl][d * 8];
            dst[0] = src[0];
            dst[1] = src[1];
        }
        __syncthreads();
        float acc = 0.f;
        #pragma unroll 8
        for (int i = 0; i < 256; i += 4) {
            float4 wv = *(const float4*)&WT[d][i];
            float4 hv = *(const float4*)&hl[nl][i];
            acc += hv.x * wv.x;
            acc += hv.y * wv.y;
            acc += hv.z * wv.z;
            acc += hv.w * wv.w;
        }
        // Wh1/Wh2 = dot over d (32-lane butterfly)
        float v1 = acc * a1;
        float v2 = acc * a2;
        #pragma unroll
        for (int s = 1; s < 32; s <<= 1) {
            v1 += __shfl_xor(v1, s);
            v2 += __shfl_xor(v2, s);
        }
        int node = nbase + c * 8 + nl;
        if (d == 0) {
            wh1s[head * 4096 + node] = v1 * LOG2E;
            wh2s[head * 4096 + node] = v2 * LOG2E;
        }
        tr[c * 8 + nl][d] = acc;
    }
    __syncthreads();
    // write WhT bf16 [h][d][n]: thread -> row d'=t>>3, 8 consecutive nodes, 16B store
    int dp = t >> 3, chunk = t & 7;
    ushort8 vv;
    #pragma unroll
    for (int k = 0; k < 8; ++k) {
        __hip_bfloat16 b = __float2bfloat16(tr[chunk * 8 + k][dp]);
        vv[k] = __builtin_bit_cast(unsigned short, b);
    }
    *(ushort8*)&whT[((size_t)(head * 32 + dp)) * 4096 + nbase + chunk * 8] = vv;
}

// ---------------- K2: fused masked softmax + PV via bf16 MFMA --------------
// block = (head, 64-row tile); 4 waves, wave w owns rows [w*16, w*16+16)
__global__ __launch_bounds__(256) void k_attn(const unsigned int* __restrict__ packed, // [4096][128]
                                              const float* __restrict__ wh1s,
                                              const float* __restrict__ wh2s,
                                              const unsigned short* __restrict__ whT,
                                              float* __restrict__ out) {               // [4096][256]
    const int head = blockIdx.y;
    const int rowbase = blockIdx.x * 64;
    const int t = threadIdx.x;
    const int w = t >> 6;
    const int lane = t & 63;
    const int r = lane & 15;     // MFMA A row / B col
    const int q = lane >> 4;     // k-quarter
    const int rloc = w * 16 + r;

    __shared__ unsigned int adjt[64][129];   // bit tile, pad 129 -> conflict-free
    __shared__ float wmx[4];

    {   // stage adjacency bit tile: 64 rows x 128 dwords
        int rr = t >> 2;
        int cc = (t & 3) * 32;
        const uint4* src = (const uint4*)&packed[(size_t)(rowbase + rr) * 128 + cc];
        #pragma unroll
        for (int k = 0; k < 8; ++k) {
            uint4 v = src[k];
            adjt[rr][cc + k * 4 + 0] = v.x;
            adjt[rr][cc + k * 4 + 1] = v.y;
            adjt[rr][cc + k * 4 + 2] = v.z;
            adjt[rr][cc + k * 4 + 3] = v.w;
        }
    }

    // per-head global max of Wh2 (softmax shift is math-invariant; no mask pass needed)
    const float* wh2p = &wh2s[(size_t)head * 4096];
    float wm = -INFINITY;
    for (int j = t; j < 4096; j += 256) wm = fmaxf(wm, wh2p[j]);
    #pragma unroll
    for (int s = 1; s < 64; s <<= 1) wm = fmaxf(wm, __shfl_xor(wm, s));
    if (lane == 0) wmx[w] = wm;
    __syncthreads();
    wm = fmaxf(fmaxf(wmx[0], wmx[1]), fmaxf(wmx[2], wmx[3]));

    const float wh1 = wh1s[(size_t)head * 4096 + rowbase + rloc];  // row r of this wave
    float sm = wh1 + wm;
    const float m = fmaxf(sm, GAT_ALPHA * sm);   // lrelu(wh1 + max Wh2), scaled domain

    f32x4 acc0 = {0.f, 0.f, 0.f, 0.f};
    f32x4 acc1 = {0.f, 0.f, 0.f, 0.f};
    float den = 0.f;

    const unsigned short* bp0 = &whT[((size_t)(head * 32) + r) * 4096];
    const unsigned short* bp1 = &whT[((size_t)(head * 32) + 16 + r) * 4096];

    for (int kt = 0; kt < 128; ++kt) {
        const int jb = kt * 32 + q * 8;
        bf16x8 b0 = *(const bf16x8*)&bp0[jb];                 // B frag ntile0 (d = r)
        bf16x8 b1 = *(const bf16x8*)&bp1[jb];                 // B frag ntile1 (d = r+16)
        unsigned int bits = (adjt[rloc][kt] >> (q * 8)) & 0xffu;
        float w2[8];
        *(float4*)&w2[0] = *(const float4*)&wh2p[jb];
        *(float4*)&w2[4] = *(const float4*)&wh2p[jb + 4];

        ushort8 pa;
        #pragma unroll
        for (int b = 0; b < 8; ++b) {
            float s = wh1 + w2[b];
            s = fmaxf(s, GAT_ALPHA * s);                      // leaky relu (scaled)
            float pe = exp2f(s - m);                          // <= 1 for active j
            pe = (bits & (1u << b)) ? pe : 0.f;               // mask
            den += pe;
            __hip_bfloat16 hb = __float2bfloat16(pe);
            pa[b] = __builtin_bit_cast(unsigned short, hb);
        }
        bf16x8 afrag = __builtin_bit_cast(bf16x8, pa);        // A frag: row r, k = 8q+b
        acc0 = __builtin_amdgcn_mfma_f32_16x16x32_bf16(afrag, b0, acc0, 0, 0, 0);
        acc1 = __builtin_amdgcn_mfma_f32_16x16x32_bf16(afrag, b1, acc1, 0, 0, 0);
    }

    // full denominator for row r: sum the 4 k-quarters
    den += __shfl_xor(den, 16);
    den += __shfl_xor(den, 32);

    // C/D layout (m89-verified): lane holds D[4*q+i][r]
    #pragma unroll
    for (int i = 0; i < 4; ++i) {
        float dn = __shfl(den, 4 * q + i);    // den of output row 4q+i
        float inv = 1.0f / dn;
        int orow = rowbase + w * 16 + 4 * q + i;
        out[(size_t)orow * 256 + head * 32 + r]      = acc0[i] * inv;
        out[(size_t)orow * 256 + head * 32 + 16 + r] = acc1[i] * inv;
    }
}

extern "C" void kernel_launch(void* const* d_in, const int* in_sizes, int n_in,
                              void* d_out, int out_size, void* d_ws, size_t ws_size,
                              hipStream_t stream) {
    const float* h   = (const float*)d_in[0];
    const int*   adj = (const int*)d_in[1];
    const float* W   = (const float*)d_in[2];
    const float* a   = (const float*)d_in[3];
    float* out = (float*)d_out;

    char* ws = (char*)d_ws;
    unsigned long long* packed = (unsigned long long*)ws;                       // 2 MB
    float* wh1s = (float*)(ws + 2 * 1024 * 1024);                               // 128 KB
    float* wh2s = (float*)(ws + 2 * 1024 * 1024 + 128 * 1024);                  // 128 KB
    unsigned short* whT = (unsigned short*)(ws + 2 * 1024 * 1024 + 256 * 1024); // 2 MB

    const int nwords = 4096 * 64;
    k_pack_adj<<<nwords * 64 / 256, 256, 0, stream>>>(adj, packed, nwords);
    k_wh<<<dim3(64, 8), 256, 0, stream>>>(h, W, a, wh1s, wh2s, whT);
    k_attn<<<dim3(64, 8), 256, 0, stream>>>((const unsigned int*)packed, wh1s, wh2s, whT, out);
}

// Round 2
// 116.668 us; speedup vs baseline: 1.1415x; 1.1415x over previous
//
#include <hip/hip_runtime.h>
#include <hip/hip_bf16.h>
#include <stdint.h>

#define GAT_ALPHA 0.2f
#define LOG2E 1.4426950408889634f

typedef __attribute__((ext_vector_type(8))) short bf16x8;
typedef __attribute__((ext_vector_type(8))) unsigned short ushort8;
typedef __attribute__((ext_vector_type(4))) float f32x4;

#if __has_builtin(__builtin_amdgcn_exp2f)
#define EXP2F(x) __builtin_amdgcn_exp2f(x)
#else
#define EXP2F(x) exp2f(x)
#endif

// ---------------- K0: pack adjacency int32 -> bitmask (64MB -> 2MB) --------
__global__ __launch_bounds__(256) void k_pack_adj(const int* __restrict__ adj,
                                                  unsigned long long* __restrict__ packed,
                                                  int nwords) {
    int gid = blockIdx.x * 256 + threadIdx.x;
    int wid = gid >> 6;               // one 64-bit word per wave
    int lane = threadIdx.x & 63;
    if (wid >= nwords) return;
    int v = adj[(size_t)wid * 64 + lane];
    unsigned long long m = __ballot(v > 0);
    if (lane == 0) packed[wid] = m;
}

// ---------------- K1: Wh = h@W[h]; Wh1/Wh2 (pre-scaled by log2e); WhT bf16 -
__global__ __launch_bounds__(256) void k_wh(const float* __restrict__ hmat,   // [4096][256]
                                            const float* __restrict__ Wmat,   // [8][256][32]
                                            const float* __restrict__ avec,   // [8][64]
                                            float* __restrict__ wh1s,         // [8][4096]  *log2e
                                            float* __restrict__ wh2s,         // [8][4096]  *log2e
                                            unsigned short* __restrict__ whT) // [8][32][4096] bf16
{
    const int head = blockIdx.y;
    const int nbase = blockIdx.x * 64;
    const int t = threadIdx.x;
    const int d = t & 31, nl = t >> 5;

    __shared__ float WT[32][260];   // W transposed [d][i]
    __shared__ float hl[8][256];    // staged h rows
    __shared__ float tr[64][33];    // transpose buffer for WhT write

    #pragma unroll
    for (int k = 0; k < 32; ++k) {
        int idx = t + k * 256;
        int ii = idx >> 5, dd = idx & 31;
        WT[dd][ii] = Wmat[(head * 256 + ii) * 32 + dd];
    }
    float a1 = avec[head * 64 + d];
    float a2 = avec[head * 64 + 32 + d];

    for (int c = 0; c < 8; ++c) {
        __syncthreads();
        {   // stage 8 rows of h
            const float4* src = (const float4*)&hmat[(size_t)(nbase + c * 8 + nl) * 256 + d * 8];
            float4* dst = (float4*)&hl[nl][d * 8];
            dst[0] = src[0];
            dst[1] = src[1];
        }
        __syncthreads();
        float acc = 0.f;
        #pragma unroll 8
        for (int i = 0; i < 256; i += 4) {
            float4 wv = *(const float4*)&WT[d][i];
            float4 hv = *(const float4*)&hl[nl][i];
            acc += hv.x * wv.x;
            acc += hv.y * wv.y;
            acc += hv.z * wv.z;
            acc += hv.w * wv.w;
        }
        float v1 = acc * a1;
        float v2 = acc * a2;
        #pragma unroll
        for (int s = 1; s < 32; s <<= 1) {
            v1 += __shfl_xor(v1, s);
            v2 += __shfl_xor(v2, s);
        }
        int node = nbase + c * 8 + nl;
        if (d == 0) {
            wh1s[head * 4096 + node] = v1 * LOG2E;
            wh2s[head * 4096 + node] = v2 * LOG2E;
        }
        tr[c * 8 + nl][d] = acc;
    }
    __syncthreads();
    int dp = t >> 3, chunk = t & 7;
    ushort8 vv;
    #pragma unroll
    for (int k = 0; k < 8; ++k) {
        __hip_bfloat16 b = __float2bfloat16(tr[chunk * 8 + k][dp]);
        vv[k] = __builtin_bit_cast(unsigned short, b);
    }
    *(ushort8*)&whT[((size_t)(head * 32 + dp)) * 4096 + nbase + chunk * 8] = vv;
}

// ---------------- K2: fused masked softmax + PV via bf16 MFMA --------------
// block = (head, 32-row tile); 4 waves: wave w -> row-tile rt=w&1 (16 rows),
// j-half jh=w>>1 (2048 j). Partials combined via LDS. Grid 128x8 -> 16 waves/CU.
__global__ __launch_bounds__(256, 4) void k_attn(const unsigned int* __restrict__ packed, // [4096][128]
                                                 const float* __restrict__ wh1s,
                                                 const float* __restrict__ wh2s,
                                                 const unsigned short* __restrict__ whT,
                                                 float* __restrict__ out) {               // [4096][256]
    const int head = blockIdx.y;
    const int rowbase = blockIdx.x * 32;
    const int t = threadIdx.x;
    const int w = t >> 6;
    const int lane = t & 63;
    const int rt = w & 1;        // row-tile within block
    const int jh = w >> 1;       // j-half
    const int r = lane & 15;     // MFMA A row / B col
    const int q = lane >> 4;     // k-quarter
    const int rloc = rt * 16 + r;

    __shared__ unsigned int adjt[32][129];   // bit tile, pad -> conflict-free
    __shared__ float wh2l[4096];             // staged (scaled) wh2 for this head
    __shared__ float wmxb[4];
    __shared__ f32x4 red[2][64][3];          // cross-wave partials

    const float* wh2p = &wh2s[(size_t)head * 4096];

    // stage wh2 (16KB) + running max
    float lmax = -INFINITY;
    #pragma unroll
    for (int k2 = 0; k2 < 4; ++k2) {
        float4 v = *(const float4*)&wh2p[t * 4 + k2 * 1024];
        *(float4*)&wh2l[t * 4 + k2 * 1024] = v;
        lmax = fmaxf(fmaxf(lmax, fmaxf(v.x, v.y)), fmaxf(v.z, v.w));
    }
    {   // stage adjacency bit tile: 32 rows x 128 dwords
        int rr = t >> 3;
        int cc = (t & 7) * 16;
        const uint4* src = (const uint4*)&packed[(size_t)(rowbase + rr) * 128 + cc];
        #pragma unroll
        for (int k2 = 0; k2 < 4; ++k2) {
            uint4 v = src[k2];
            adjt[rr][cc + k2 * 4 + 0] = v.x;
            adjt[rr][cc + k2 * 4 + 1] = v.y;
            adjt[rr][cc + k2 * 4 + 2] = v.z;
            adjt[rr][cc + k2 * 4 + 3] = v.w;
        }
    }
    #pragma unroll
    for (int s = 1; s < 64; s <<= 1) lmax = fmaxf(lmax, __shfl_xor(lmax, s));
    if (lane == 0) wmxb[w] = lmax;
    __syncthreads();
    const float wm = fmaxf(fmaxf(wmxb[0], wmxb[1]), fmaxf(wmxb[2], wmxb[3]));

    // per-row constants (scaled domain; m = lrelu(wh1 + max wh2) >= all scores)
    const float wh1 = wh1s[(size_t)head * 4096 + rowbase + rloc];
    const float sm0 = wh1 + wm;
    const float m = fmaxf(sm0, GAT_ALPHA * sm0);
    const float wh1m = wh1 - m;                 // for s > 0 branch
    const float c2 = GAT_ALPHA * wh1 - m;       // for s < 0 branch (fma with alpha*w2)

    f32x4 acc0 = {0.f, 0.f, 0.f, 0.f};
    f32x4 acc1 = {0.f, 0.f, 0.f, 0.f};
    f32x4 accd = {0.f, 0.f, 0.f, 0.f};          // row-sum (denominator) via ones-MFMA

    ushort8 onesu;
    #pragma unroll
    for (int b = 0; b < 8; ++b) onesu[b] = 0x3F80;  // bf16 1.0
    const bf16x8 ones = __builtin_bit_cast(bf16x8, onesu);

    const unsigned short* bp0 = &whT[((size_t)(head * 32) + r) * 4096];
    const unsigned short* bp1 = &whT[((size_t)(head * 32) + 16 + r) * 4096];

    const int kt0 = jh * 64;
    for (int kt = kt0; kt < kt0 + 64; ++kt) {
        const int jb = kt * 32 + q * 8;
        bf16x8 b0 = *(const bf16x8*)&bp0[jb];
        bf16x8 b1 = *(const bf16x8*)&bp1[jb];
        unsigned int bits = (adjt[rloc][kt] >> (q * 8)) & 0xffu;
        float w2[8];
        *(float4*)&w2[0] = *(const float4*)&wh2l[jb];
        *(float4*)&w2[4] = *(const float4*)&wh2l[jb + 4];

        ushort8 pa;
        #pragma unroll
        for (int b = 0; b < 8; ++b) {
            float u = wh1m + w2[b];                       // s - m   (s>0 case)
            float tv = fmaf(GAT_ALPHA, w2[b], c2);        // a*s - m (s<0 case)
            float s = fmaxf(u, tv);                       // lrelu(s) - m, <= 0
            float pe = EXP2F(s);
            pe = (bits & (1u << b)) ? pe : 0.f;
            __hip_bfloat16 hb = __float2bfloat16(pe);
            pa[b] = __builtin_bit_cast(unsigned short, hb);
        }
        bf16x8 af = __builtin_bit_cast(bf16x8, pa);
        acc0 = __builtin_amdgcn_mfma_f32_16x16x32_bf16(af, b0, acc0, 0, 0, 0);
        acc1 = __builtin_amdgcn_mfma_f32_16x16x32_bf16(af, b1, acc1, 0, 0, 0);
        accd = __builtin_amdgcn_mfma_f32_16x16x32_bf16(af, ones, accd, 0, 0, 0);
    }

    // combine j-halves: jh=1 waves publish, jh=0 waves finalize
    if (jh == 1) {
        red[rt][lane][0] = acc0;
        red[rt][lane][1] = acc1;
        red[rt][lane][2] = accd;
    }
    __syncthreads();
    if (jh == 0) {
        acc0 += red[rt][lane][0];
        acc1 += red[rt][lane][1];
        accd += red[rt][lane][2];
        // C/D layout: lane holds D[4q+i][r]; accd[i] = den of row 4q+i
        #pragma unroll
        for (int i = 0; i < 4; ++i) {
            float inv = 1.0f / accd[i];
            int orow = rowbase + rt * 16 + 4 * q + i;
            out[(size_t)orow * 256 + head * 32 + r]      = acc0[i] * inv;
            out[(size_t)orow * 256 + head * 32 + 16 + r] = acc1[i] * inv;
        }
    }
}

extern "C" void kernel_launch(void* const* d_in, const int* in_sizes, int n_in,
                              void* d_out, int out_size, void* d_ws, size_t ws_size,
                              hipStream_t stream) {
    const float* h   = (const float*)d_in[0];
    const int*   adj = (const int*)d_in[1];
    const float* W   = (const float*)d_in[2];
    const float* a   = (const float*)d_in[3];
    float* out = (float*)d_out;

    char* ws = (char*)d_ws;
    unsigned long long* packed = (unsigned long long*)ws;                       // 2 MB
    float* wh1s = (float*)(ws + 2 * 1024 * 1024);                               // 128 KB
    float* wh2s = (float*)(ws + 2 * 1024 * 1024 + 128 * 1024);                  // 128 KB
    unsigned short* whT = (unsigned short*)(ws + 2 * 1024 * 1024 + 256 * 1024); // 2 MB

    const int nwords = 4096 * 64;
    k_pack_adj<<<nwords * 64 / 256, 256, 0, stream>>>(adj, packed, nwords);
    k_wh<<<dim3(64, 8), 256, 0, stream>>>(h, W, a, wh1s, wh2s, whT);
    k_attn<<<dim3(128, 8), 256, 0, stream>>>((const unsigned int*)packed, wh1s, wh2s, whT, out);
}